// Round 13
// baseline (141.024 us; speedup 1.0000x reference)
//
#include <hip/hip_runtime.h>
#include <hip/hip_bf16.h>
#include <math.h>

// Problem constants
#define BATCH   8
#define S_LEN   1024
#define D_MODEL 1280
#define DX      768
#define NH      8
#define HD      160
#define LTXT    77
#define MKV_PAD 640             // 616 padded to 128-multiple
#define MQ      (BATCH*S_LEN)   // 8192
#define MKV     (BATCH*LTXT)    // 616
#define HL      80              // per-head padded l-stride
#define NHL     640             // 8*80
#define KPAD    192             // 160 padded to 64-multiple
#define KVROWS  5184            // 64*77=4928 + slack for 128-row tile overrun

typedef _Float16 f16x8 __attribute__((ext_vector_type(8)));
typedef _Float16 f16x4 __attribute__((ext_vector_type(4)));
typedef float    f32x4 __attribute__((ext_vector_type(4)));

// ---------------------------------------------------------------------------
// Fused prep kernel: all input-only conversions + zero-fills in ONE launch.
// ---------------------------------------------------------------------------
#define NB_HID 10240   // 8192*1280/4/256
#define NB_ENC 480     // 640*768/4/256
#define NB_WQP 1600    // plain f16 copy of Wq (1280*1280/4/256)
#define NB_WOT 1600    // transpose Wo
#define NB_WK  960
#define NB_WV  960
#define NB_ZK  972     // zero kf2 (5184*192/4/256)
#define NB_ZV  972     // zero vf2
#define NB_PREP (NB_HID+NB_ENC+NB_WQP+NB_WOT+NB_WK+NB_WV+NB_ZK+NB_ZV)

__device__ inline void to_f16_dev(const float* __restrict__ X,
                                  _Float16* __restrict__ Y,
                                  int K, int Mreal, int bid)
{
    const size_t g = ((size_t)bid * 256 + threadIdx.x) * 4;
    const int row = (int)(g / K);
    float4 x = make_float4(0.f, 0.f, 0.f, 0.f);
    if (row < Mreal) x = *(const float4*)&X[g];
    f16x4 o;
    o[0] = (_Float16)x.x; o[1] = (_Float16)x.y;
    o[2] = (_Float16)x.z; o[3] = (_Float16)x.w;
    *(f16x4*)&Y[g] = o;
}

__device__ inline void zero_f16_dev(_Float16* __restrict__ Y, int bid)
{
    const size_t g = ((size_t)bid * 256 + threadIdx.x) * 4;
    f16x4 z;
    z[0] = (_Float16)0.f; z[1] = (_Float16)0.f;
    z[2] = (_Float16)0.f; z[3] = (_Float16)0.f;
    *(f16x4*)&Y[g] = z;
}

__device__ inline void wt_t_dev(const float* __restrict__ W,
                                _Float16* __restrict__ BT,
                                int K, int N, int KLD, int noff,
                                int bx, int by, float (*tile)[33])
{
    const int k0 = by * 32, n0 = bx * 32;
    const int tx = threadIdx.x & 31, ty = threadIdx.x >> 5;
#pragma unroll
    for (int r = 0; r < 32; r += 8)
        tile[r + ty][tx] = W[(size_t)(k0 + r + ty) * N + n0 + tx];
    __syncthreads();
#pragma unroll
    for (int r = 0; r < 32; r += 8) {
        const int n = noff + n0 + r + ty, k = k0 + tx;
        BT[(size_t)n * KLD + k] = (_Float16)tile[tx][r + ty];
    }
}

__global__ __launch_bounds__(256) void prep_kernel(
    const float* __restrict__ hidden, const float* __restrict__ enc,
    const float* __restrict__ Wq, const float* __restrict__ Wk,
    const float* __restrict__ Wv, const float* __restrict__ Wo,
    _Float16* __restrict__ hidf, _Float16* __restrict__ encb,
    _Float16* __restrict__ Wqp, _Float16* __restrict__ WoT,
    _Float16* __restrict__ B2Tkv,
    _Float16* __restrict__ kf2, _Float16* __restrict__ vf2)
{
    __shared__ float tile[32][33];
    int bid = blockIdx.x;
    if (bid < NB_HID) { to_f16_dev(hidden, hidf, D_MODEL, MQ, bid); return; }
    bid -= NB_HID;
    if (bid < NB_ENC) { to_f16_dev(enc, encb, DX, MKV, bid); return; }
    bid -= NB_ENC;
    if (bid < NB_WQP) { to_f16_dev(Wq, Wqp, D_MODEL, D_MODEL, bid); return; }
    bid -= NB_WQP;
    if (bid < NB_WOT) { wt_t_dev(Wo, WoT, D_MODEL, D_MODEL, D_MODEL, 0, bid % 40, bid / 40, tile); return; }
    bid -= NB_WOT;
    if (bid < NB_WK)  { wt_t_dev(Wk, B2Tkv, DX, D_MODEL, DX, 0, bid % 40, bid / 40, tile); return; }
    bid -= NB_WK;
    if (bid < NB_WV)  { wt_t_dev(Wv, B2Tkv, DX, D_MODEL, DX, D_MODEL, bid % 40, bid / 40, tile); return; }
    bid -= NB_WV;
    if (bid < NB_ZK)  { zero_f16_dev(kf2, bid); return; }
    bid -= NB_ZK;
    zero_f16_dev(vf2, bid);
}

// ---------------------------------------------------------------------------
// Hot MFMA fp16 GEMM (r6/r11 proven core, UNTOUCHED inner loop), batched:
// C_b[M,N] = A_b[M,KK] @ B_b[N,KK]^T. blockIdx -> (batch, mt, nt) via tpb.
// 128x128 tile, BK=64, 4 waves, single 32KB LDS, T2 swizzle, T1 XCD swizzle.
// Modes (runtime-uniform, epilogue-only -- r10 lesson: no templates, no
// duplicated call sites; 3 modes matched the proven r6 kernel's VGPR 84):
//   kout!=0 : K->kf2[(b8+h)77+l][KPAD] f16 / V->vout[row][1280] f32, row<Mreal
//   Ch!=0   : f16 batched store (scores)
//   else    : Cf[(b*CB+row)*N+col] = v + bias (fp32 out)
// ---------------------------------------------------------------------------
__device__ inline void async_copy16(const void* gptr, void* lptr) {
    __builtin_amdgcn_global_load_lds(
        (const __attribute__((address_space(1))) unsigned*)gptr,
        (__attribute__((address_space(3))) unsigned*)lptr, 16, 0, 0);
}

__global__ __launch_bounds__(256) void gemm_mfma_bt(
    const _Float16* __restrict__ A, const _Float16* __restrict__ B,
    float* __restrict__ Cf, _Float16* __restrict__ Ch,
    _Float16* __restrict__ kout, float* __restrict__ vout,
    const float* __restrict__ bias,
    int Mreal, int N, int KK, int ntn, int tpb, int AB, int BB, int CB)
{
    __shared__ __align__(16) _Float16 As[128 * 64];  // 16 KB
    __shared__ __align__(16) _Float16 Bs[128 * 64];  // 16 KB
    const int t = threadIdx.x;
    const int wave = t >> 6, lane = t & 63;
    const int lr = lane & 15, lg = lane >> 4;
    const int wr = wave >> 1, wc = wave & 1;

    // T1 bijective XCD-chunk swizzle (m204)
    const int nwg = gridDim.x;
    const int q = nwg >> 3, r = nwg & 7;
    const int xcd = blockIdx.x & 7, idx = blockIdx.x >> 3;
    const int swz = (xcd < r ? xcd * (q + 1) : r * (q + 1) + (xcd - r) * q) + idx;
    const int b  = swz / tpb;
    const int lc = swz % tpb;
    const int m0 = (lc / ntn) * 128, n0 = (lc % ntn) * 128;
    const size_t arow0 = (size_t)b * AB + m0;
    const size_t brow0 = (size_t)b * BB + n0;

    f32x4 acc[4][4] = {};

    const int sr = lane >> 3;                   // row within staging instr
    const int sk = 8 * ((lane & 7) ^ sr);       // T2 pre-swizzled k-elem offset

    for (int k0 = 0; k0 < KK; k0 += 64) {
        __syncthreads();   // previous compute done
#pragma unroll
        for (int s = 0; s < 4; ++s) {
            const int ti = wave * 4 + s;
            const int row = ti * 8 + sr;
            async_copy16(A + (arow0 + row) * KK + k0 + sk, As + ti * 512);
            async_copy16(B + (brow0 + row) * KK + k0 + sk, Bs + ti * 512);
        }
        __syncthreads();   // staging complete (barrier drains vmcnt)

        f16x8 af[4][2], bf_[4][2];
#pragma unroll
        for (int i = 0; i < 4; ++i)
#pragma unroll
            for (int ki = 0; ki < 2; ++ki) {
                const int koff = (ki * 32 + lg * 8) ^ ((lr & 7) * 8);
                af[i][ki]  = *(const f16x8*)(As + (wr * 64 + i * 16 + lr) * 64 + koff);
                bf_[i][ki] = *(const f16x8*)(Bs + (wc * 64 + i * 16 + lr) * 64 + koff);
            }
#pragma unroll
        for (int ki = 0; ki < 2; ++ki)
#pragma unroll
            for (int i = 0; i < 4; ++i)
#pragma unroll
                for (int j = 0; j < 4; ++j)
                    acc[i][j] = __builtin_amdgcn_mfma_f32_16x16x32_f16(
                        af[i][ki], bf_[j][ki], acc[i][j], 0, 0, 0);
    }

    // epilogue: C row = lg*4 + rr, col = lr within fragment (m89 layout)
#pragma unroll
    for (int i = 0; i < 4; ++i) {
#pragma unroll
        for (int j = 0; j < 4; ++j) {
            const int col = n0 + wc * 64 + j * 16 + lr;
            const float bv = bias ? bias[col] : 0.f;
#pragma unroll
            for (int rr = 0; rr < 4; ++rr) {
                const int row = m0 + wr * 64 + i * 16 + lg * 4 + rr;
                const float v = acc[i][j][rr] + bv;
                if (kout) {
                    if (row < Mreal) {
                        if (col < D_MODEL) {
                            const int h = col / HD, d = col % HD;
                            const int bb = row / LTXT, ll = row % LTXT;
                            kout[((size_t)((bb * 8 + h) * LTXT + ll)) * KPAD + d] = (_Float16)v;
                        } else {
                            vout[(size_t)row * D_MODEL + col - D_MODEL] = v;
                        }
                    }
                } else if (Ch) {
                    Ch[((size_t)(b * CB + row)) * N + col] = (_Float16)v;
                } else {
                    Cf[((size_t)(b * CB + row)) * N + col] = v;
                }
            }
        }
    }
}

// ---------------------------------------------------------------------------
// Small MFMA GEMM for the rank-77 folds (S~ and V~), fully arg-driven.
// Separate kernel so the hot kernel's regalloc is untouched (r10 lesson).
// ---------------------------------------------------------------------------
__global__ __launch_bounds__(256) void gemm_small(
    const _Float16* __restrict__ A, const _Float16* __restrict__ B,
    _Float16* __restrict__ Co,
    int mtn, int ntn, int Mg, int Ng,
    int astride, int bstride, int ostride,
    int aBH, int bBH, int aH, int bH,
    int oB, int oH, int oC)
{
    __shared__ __align__(16) _Float16 As[128 * 64];
    __shared__ __align__(16) _Float16 Bs[128 * 64];
    const int t = threadIdx.x;
    const int wave = t >> 6, lane = t & 63;
    const int lr = lane & 15, lg = lane >> 4;
    const int wr = wave >> 1, wc = wave & 1;

    const int nwg = gridDim.x;
    const int q = nwg >> 3, r = nwg & 7;
    const int xcd = blockIdx.x & 7, idx = blockIdx.x >> 3;
    const int swz = (xcd < r ? xcd * (q + 1) : r * (q + 1) + (xcd - r) * q) + idx;
    const int tpb = mtn * ntn;
    const int bh = swz / tpb;
    const int lc = swz % tpb;
    const int m0 = (lc / ntn) * 128, n0 = (lc % ntn) * 128;
    const int b = bh >> 3, h = bh & 7;

    const size_t abase = (size_t)bh * aBH + m0;
    const size_t bbase = (size_t)bh * bBH + n0;
    const int aoff = h * aH, boff = h * bH;

    f32x4 acc[4][4] = {};

    const int sr = lane >> 3;
    const int sk = 8 * ((lane & 7) ^ sr);

    for (int k0 = 0; k0 < KPAD; k0 += 64) {
        __syncthreads();
#pragma unroll
        for (int s = 0; s < 4; ++s) {
            const int ti = wave * 4 + s;
            const int row = ti * 8 + sr;
            async_copy16(A + (abase + row) * astride + aoff + k0 + sk, As + ti * 512);
            async_copy16(B + (bbase + row) * bstride + boff + k0 + sk, Bs + ti * 512);
        }
        __syncthreads();

        f16x8 af[4][2], bf_[4][2];
#pragma unroll
        for (int i = 0; i < 4; ++i)
#pragma unroll
            for (int ki = 0; ki < 2; ++ki) {
                const int koff = (ki * 32 + lg * 8) ^ ((lr & 7) * 8);
                af[i][ki]  = *(const f16x8*)(As + (wr * 64 + i * 16 + lr) * 64 + koff);
                bf_[i][ki] = *(const f16x8*)(Bs + (wc * 64 + i * 16 + lr) * 64 + koff);
            }
#pragma unroll
        for (int ki = 0; ki < 2; ++ki)
#pragma unroll
            for (int i = 0; i < 4; ++i)
#pragma unroll
                for (int j = 0; j < 4; ++j)
                    acc[i][j] = __builtin_amdgcn_mfma_f32_16x16x32_f16(
                        af[i][ki], bf_[j][ki], acc[i][j], 0, 0, 0);
    }

#pragma unroll
    for (int i = 0; i < 4; ++i) {
#pragma unroll
        for (int j = 0; j < 4; ++j) {
            const int n = n0 + wc * 64 + j * 16 + lr;
#pragma unroll
            for (int rr = 0; rr < 4; ++rr) {
                const int m = m0 + wr * 64 + i * 16 + lg * 4 + rr;
                if (m < Mg && n < Ng)
                    Co[((size_t)(b * oB + h * oH + m)) * ostride + h * oC + n] =
                        (_Float16)acc[i][j][rr];
            }
        }
    }
}

// ---------------------------------------------------------------------------
// Ortho-decomp retain transform: reads fp32 V [616,1280], writes f16
// vf2[(b*8+h)*77+l][KPAD] (tails pre-zeroed by prep).
// ---------------------------------------------------------------------------
__global__ __launch_bounds__(256) void retain_kernel(
    const float* __restrict__ vbuf, _Float16* __restrict__ vf2,
    const float* __restrict__ tv)
{
    const int l = blockIdx.x % LTXT;
    const int r = blockIdx.x / LTXT;
    const int t = threadIdx.x;

    float g00=0,g01=0,g02=0,g11=0,g12=0,g22=0,tp0=0,tp1=0,tp2=0,pp=0;
    float p_save[10], t0s[10], t1s[10], t2s[10];
#pragma unroll
    for (int it = 0; it < 10; ++it) {
        const int j   = t + it * 256;
        const int m16 = j / HD, d = j % HD;
        const int e = m16 >> 3, h = m16 & 7;
        const float T0 = tv[((size_t)(e*24 +  0 + h) * LTXT + l) * HD + d];
        const float T1 = tv[((size_t)(e*24 +  8 + h) * LTXT + l) * HD + d];
        const float T2 = tv[((size_t)(e*24 + 16 + h) * LTXT + l) * HD + d];
        const float p  = vbuf[((size_t)((e*4 + r) * LTXT + l)) * D_MODEL + h*HD + d];
        p_save[it] = p; t0s[it] = T0; t1s[it] = T1; t2s[it] = T2;
        g00 += T0*T0; g01 += T0*T1; g02 += T0*T2;
        g11 += T1*T1; g12 += T1*T2; g22 += T2*T2;
        tp0 += T0*p;  tp1 += T1*p;  tp2 += T2*p;  pp += p*p;
    }

    __shared__ float part[4][10];
    const int wave = t >> 6, lane = t & 63;
    float vals[10] = {g00,g01,g02,g11,g12,g22,tp0,tp1,tp2,pp};
#pragma unroll
    for (int i = 0; i < 10; ++i) {
        float x = vals[i];
        x += __shfl_down(x, 32); x += __shfl_down(x, 16);
        x += __shfl_down(x,  8); x += __shfl_down(x,  4);
        x += __shfl_down(x,  2); x += __shfl_down(x,  1);
        if (lane == 0) part[wave][i] = x;
    }
    __syncthreads();

    float s[10];
#pragma unroll
    for (int i = 0; i < 10; ++i)
        s[i] = part[0][i] + part[1][i] + part[2][i] + part[3][i];

    const float G[3][3] = {{s[0],s[1],s[2]},{s[1],s[3],s[4]},{s[2],s[4],s[5]}};
    const float tp[3] = {s[6], s[7], s[8]};
    const float ppv = s[9];

    float Pm[3][3];
#pragma unroll
    for (int c = 0; c < 3; ++c)
#pragma unroll
        for (int e = 0; e < 3; ++e) {
            float v = (c == e) ? 1.f : 0.f;
            if (c > e) v -= G[c][e] / G[e][e];
            Pm[c][e] = v;
        }

    const float nP = fmaxf(sqrtf(ppv), 1e-8f);
    float w[3], cosg[3];
#pragma unroll
    for (int c = 0; c < 3; ++c) {
        const float nT = fmaxf(sqrtf(G[c][c]), 1e-8f);
        const float cosv = tp[c] / (nT * nP);
        cosg[c] = 1.f / (1.f + expf(-10.f * (cosv - 0.5f)));
        float d1 = Pm[c][0]*tp[0] + Pm[c][1]*tp[1] + Pm[c][2]*tp[2];
        float d2 = 0.f;
#pragma unroll
        for (int e = 0; e < 3; ++e)
#pragma unroll
            for (int f = 0; f < 3; ++f) d2 += Pm[c][e] * Pm[c][f] * G[e][f];
        float wc = d1 / d2;
        if (isnan(wc)) wc = 0.f;
        if (l == 0)    wc = 0.f;
        w[c] = wc;
    }

    float coef[3];
#pragma unroll
    for (int e = 0; e < 3; ++e)
        coef[e] = cosg[e] * (w[0]*Pm[0][e] + w[1]*Pm[1][e] + w[2]*Pm[2][e]);

#pragma unroll
    for (int it = 0; it < 10; ++it) {
        const int j   = t + it * 256;
        const int m16 = j / HD, d = j % HD;
        const int e = m16 >> 3, h = m16 & 7;
        const float era = coef[0]*t0s[it] + coef[1]*t1s[it] + coef[2]*t2s[it];
        vf2[((size_t)(((e*4 + r) * 8 + h) * LTXT + l)) * KPAD + d] =
            (_Float16)(p_save[it] - era);
    }
}

// ---------------------------------------------------------------------------
// Softmax: scores f16 [8192, 640(=8 heads x 80)] -> P~ f16 same layout.
// One wave per row; 8 lanes per head (10 cols/lane); pad cols l>=77 -> 0.
// ---------------------------------------------------------------------------
__global__ __launch_bounds__(256) void softmax_kernel(
    const _Float16* __restrict__ sc, _Float16* __restrict__ P)
{
    const int row = blockIdx.x * 4 + (threadIdx.x >> 6);
    const int lane = threadIdx.x & 63;
    const int s = lane & 7;                 // lane position within head group
    const unsigned* rp = (const unsigned*)(sc + (size_t)row * NHL) + lane * 5;
    float v[10];
#pragma unroll
    for (int j = 0; j < 5; ++j) {
        union { unsigned u; _Float16 h[2]; } cv;
        cv.u = rp[j];
        v[2*j]   = (float)cv.h[0];
        v[2*j+1] = (float)cv.h[1];
    }
    const int nreal = (s == 7) ? 7 : 10;    // lane 7 of group: cols 70..76 real

    float mx = -1e30f;
#pragma unroll
    for (int j = 0; j < 10; ++j) if (j < nreal) mx = fmaxf(mx, v[j]);
    mx = fmaxf(mx, __shfl_xor(mx, 1));
    mx = fmaxf(mx, __shfl_xor(mx, 2));
    mx = fmaxf(mx, __shfl_xor(mx, 4));

    const float scale = 0.07905694150420949f;  // 1/sqrt(160)
    float sum = 0.f;
#pragma unroll
    for (int j = 0; j < 10; ++j) {
        const float e = (j < nreal) ? __expf((v[j] - mx) * scale) : 0.f;
        v[j] = e; sum += e;
    }
    sum += __shfl_xor(sum, 1);
    sum += __shfl_xor(sum, 2);
    sum += __shfl_xor(sum, 4);
    const float inv = 1.f / sum;

    _Float16* op = P + (size_t)row * NHL + lane * 10;
#pragma unroll
    for (int j = 0; j < 5; ++j) {
        const _Float16 a = (_Float16)(v[2*j] * inv);
        const _Float16 b = (_Float16)(v[2*j+1] * inv);
        ushort2 u;
        u.x = *(const unsigned short*)&a;
        u.y = *(const unsigned short*)&b;
        *(ushort2*)(op + 2*j) = u;
    }
}

// ---------------------------------------------------------------------------
extern "C" void kernel_launch(void* const* d_in, const int* in_sizes, int n_in,
                              void* d_out, int out_size, void* d_ws, size_t ws_size,
                              hipStream_t stream)
{
    const float* hidden = (const float*)d_in[0]; // [8,1024,1280]
    const float* enc    = (const float*)d_in[1]; // [8,77,768]
    const float* Wq     = (const float*)d_in[2]; // [1280,1280]
    const float* Wk     = (const float*)d_in[3]; // [768,1280]
    const float* Wv     = (const float*)d_in[4]; // [768,1280]
    const float* Wo     = (const float*)d_in[5]; // [1280,1280]
    const float* bo     = (const float*)d_in[6]; // [1280]
    const float* tv     = (const float*)d_in[7]; // [48,77,160]
    float* out = (float*)d_out;

    // ws layout
    _Float16* kf2   = (_Float16*)d_ws;                           // [5184, 192]
    _Float16* vf2   = kf2 + (size_t)KVROWS * KPAD;               // [5184, 192]
    float*    vbuf  = (float*)(vf2 + (size_t)KVROWS * KPAD);     // [616, 1280] f32
    _Float16* Wqp   = (_Float16*)(vbuf + (size_t)MKV * D_MODEL); // [1280*1280 +192]
    _Float16* WoT   = Wqp + (size_t)D_MODEL * D_MODEL + 192;     // [1280*1280 +192]
    _Float16* B2Tkv = WoT + (size_t)D_MODEL * D_MODEL + 192;     // [2560, 768]
    _Float16* encb  = B2Tkv + (size_t)2 * D_MODEL * DX;          // [640, 768]
    _Float16* Sb    = encb + (size_t)MKV_PAD * DX;               // [8*640, 1280]
    _Float16* Vt    = Sb + (size_t)BATCH * NHL * D_MODEL;        // [8*1280, 640]
    _Float16* scf   = Vt + (size_t)BATCH * D_MODEL * NHL;        // [8192, 640] f16
    _Float16* hidf  = scf + (size_t)MQ * NHL;                    // [8192, 1280]
    _Float16* Pt    = hidf;   // P~ [8192,640] aliases hidf (dead after scores-GEMM)

    // 1. conversions / transposes / zero-fills
    prep_kernel<<<NB_PREP, 256, 0, stream>>>(
        hidden, enc, Wq, Wk, Wv, Wo, hidf, encb, Wqp, WoT, B2Tkv, kf2, vf2);

    // 2. K|V projection: K -> kf2 (head-grouped f16), V -> vbuf f32
    gemm_mfma_bt<<<100, 256, 0, stream>>>(
        encb, B2Tkv, nullptr, nullptr, kf2, vbuf, nullptr,
        MKV, 2 * D_MODEL, DX, 20, 100, 0, 0, 0);

    // 3. retain transform: vbuf f32 -> vf2 f16 (head-grouped)
    retain_kernel<<<4 * LTXT, 256, 0, stream>>>(vbuf, vf2, tv);

    // 4. S~T[b][h*80+l][D] = sum_d kf2 * Wq   (M=77 guarded, N=1280, K=192)
    gemm_small<<<640, 256, 0, stream>>>(
        kf2, Wqp, Sb,
        /*mtn,ntn*/ 1, 10, /*Mg,Ng*/ LTXT, D_MODEL,
        /*astride,bstride,ostride*/ KPAD, D_MODEL, D_MODEL,
        /*aBH,bBH*/ LTXT, 0, /*aH,bH*/ 0, HD,
        /*oB,oH,oC*/ NHL, HL, 0);

    // 5. V~T[b][n][h*80+l] = sum_d WoT * vf2  (M=1280, N=77 guarded, K=192)
    gemm_small<<<640, 256, 0, stream>>>(
        WoT, vf2, Vt,
        /*mtn,ntn*/ 10, 1, /*Mg,Ng*/ D_MODEL, LTXT,
        /*astride,bstride,ostride*/ D_MODEL, KPAD, NHL,
        /*aBH,bBH*/ 0, LTXT, /*aH,bH*/ HD, 0,
        /*oB,oH,oC*/ D_MODEL, 0, HL);

    // 6. scores_b = hidf_b @ S~T_b^T  (batched 8: M=1024, N=640, K=1280) f16
    gemm_mfma_bt<<<320, 256, 0, stream>>>(
        hidf, Sb, nullptr, scf, nullptr, nullptr, nullptr,
        1024, NHL, D_MODEL, 5, 40, 1024, NHL, 1024);

    // 7. softmax (scale inside): f16 scores -> P~ f16 (pads zeroed)
    softmax_kernel<<<MQ / 4, 256, 0, stream>>>(scf, Pt);

    // 8. out_b = P~_b @ V~T_b^T + bo  (batched 8: M=1024, N=1280, K=640) f32
    gemm_mfma_bt<<<640, 256, 0, stream>>>(
        Pt, Vt, out, nullptr, nullptr, nullptr, bo,
        1024, D_MODEL, NHL, 10, 80, 1024, D_MODEL, 1024);
}